// Round 2
// baseline (70.732 us; speedup 1.0000x reference)
//
#include <hip/hip_runtime.h>

// CrossNet fused: one block per row. Closed form x_k = x*c_k + cumsum(b),
// c_k per-row scalar from 3 dot products + 2 shared constants.
// N = 4096, BLK = 256 -> 4 float4 chunks per thread.
// R2: nontemporal loads/stores for the streaming data (x, out),
//     stream-grouped epilogue stores (16 KB sequential bursts per stream).

constexpr int BLK = 256;

typedef float f32x4 __attribute__((ext_vector_type(4)));

__global__ __launch_bounds__(BLK) void crossnet_fused(
    const float* __restrict__ x,
    const float* __restrict__ w,
    const float* __restrict__ b,
    float* __restrict__ out,
    int B, int N)
{
    const int row = blockIdx.x;
    const int tid = threadIdx.x;

    const size_t base = (size_t)row * N;
    const f32x4* x4 = (const f32x4*)(x + base);
    const f32x4* w0 = (const f32x4*)(w);
    const f32x4* w1 = (const f32x4*)(w + N);
    const f32x4* w2 = (const f32x4*)(w + 2 * (size_t)N);
    const f32x4* b0 = (const f32x4*)(b);
    const f32x4* b1 = (const f32x4*)(b + N);
    const f32x4* b2 = (const f32x4*)(b + 2 * (size_t)N);

    // Register-resident row data: x, and cumulative bias sums
    f32x4 xv[4];
    f32x4 cb1v[4];  // b0
    f32x4 cb2v[4];  // b0+b1
    f32x4 cb3v[4];  // b0+b1+b2

    float p0 = 0.f, p1 = 0.f, p2 = 0.f;  // x . w0/w1/w2 partials
    float q1 = 0.f, q2 = 0.f;            // b0 . w1, (b0+b1) . w2 partials

    #pragma unroll
    for (int c = 0; c < 4; ++c) {
        const int idx = c * BLK + tid;     // float4 index within the row
        const f32x4 xx = __builtin_nontemporal_load(&x4[idx]);  // read-once stream
        const f32x4 wa = w0[idx];   // cacheable: reused by all blocks
        const f32x4 wb = w1[idx];
        const f32x4 wc = w2[idx];
        const f32x4 ba = b0[idx];
        const f32x4 bb = b1[idx];
        const f32x4 bc = b2[idx];

        xv[c] = xx;
        const f32x4 c1v = ba;
        const f32x4 c2v = ba + bb;
        const f32x4 c3v = c2v + bc;
        cb1v[c] = c1v; cb2v[c] = c2v; cb3v[c] = c3v;

        p0 += xx.x * wa.x + xx.y * wa.y + xx.z * wa.z + xx.w * wa.w;
        p1 += xx.x * wb.x + xx.y * wb.y + xx.z * wb.z + xx.w * wb.w;
        p2 += xx.x * wc.x + xx.y * wc.y + xx.z * wc.z + xx.w * wc.w;
        q1 += c1v.x * wb.x + c1v.y * wb.y + c1v.z * wb.z + c1v.w * wb.w;
        q2 += c2v.x * wc.x + c2v.y * wc.y + c2v.z * wc.z + c2v.w * wc.w;
    }

    // Wave-level butterfly reduce (64 lanes)
    #pragma unroll
    for (int off = 32; off > 0; off >>= 1) {
        p0 += __shfl_down(p0, off);
        p1 += __shfl_down(p1, off);
        p2 += __shfl_down(p2, off);
        q1 += __shfl_down(q1, off);
        q2 += __shfl_down(q2, off);
    }

    __shared__ float red[4][8];
    const int wave = tid >> 6;
    const int lane = tid & 63;
    if (lane == 0) {
        red[wave][0] = p0; red[wave][1] = p1; red[wave][2] = p2;
        red[wave][3] = q1; red[wave][4] = q2;
    }
    __syncthreads();

    const float u0 = red[0][0] + red[1][0] + red[2][0] + red[3][0];
    const float u1 = red[0][1] + red[1][1] + red[2][1] + red[3][1];
    const float u2 = red[0][2] + red[1][2] + red[2][2] + red[3][2];
    const float t1 = red[0][3] + red[1][3] + red[2][3] + red[3][3];
    const float t2 = red[0][4] + red[1][4] + red[2][4] + red[3][4];

    // scalar recurrence
    const float c1 = 1.0f + u0;            // x1 = x*c1 + b0
    const float s1 = c1 * u1 + t1;
    const float c2 = c1 + s1;              // x2 = x*c2 + b0+b1
    const float s2 = c2 * u2 + t2;
    const float c3 = c2 + s2;              // x3 = x*c3 + b0+b1+b2

    f32x4* o0 = (f32x4*)(out + base);
    f32x4* o1 = (f32x4*)(out + (size_t)B * N + base);
    f32x4* o2 = (f32x4*)(out + 2 * (size_t)B * N + base);

    // Stream-grouped nontemporal stores: 16 KB sequential burst per stream.
    #pragma unroll
    for (int c = 0; c < 4; ++c) {
        const int idx = c * BLK + tid;
        const f32x4 r = xv[c] * c1 + cb1v[c];
        __builtin_nontemporal_store(r, &o0[idx]);
    }
    #pragma unroll
    for (int c = 0; c < 4; ++c) {
        const int idx = c * BLK + tid;
        const f32x4 r = xv[c] * c2 + cb2v[c];
        __builtin_nontemporal_store(r, &o1[idx]);
    }
    #pragma unroll
    for (int c = 0; c < 4; ++c) {
        const int idx = c * BLK + tid;
        const f32x4 r = xv[c] * c3 + cb3v[c];
        __builtin_nontemporal_store(r, &o2[idx]);
    }
}

extern "C" void kernel_launch(void* const* d_in, const int* in_sizes, int n_in,
                              void* d_out, int out_size, void* d_ws, size_t ws_size,
                              hipStream_t stream) {
    const float* x = (const float*)d_in[0];
    const float* w = (const float*)d_in[1];
    const float* b = (const float*)d_in[2];
    float* out = (float*)d_out;

    const int N = in_sizes[1] / 3;   // w is [3, N, 1]
    const int B = in_sizes[0] / N;   // x is [B, N]

    crossnet_fused<<<B, BLK, 0, stream>>>(x, w, b, out, B, N);
}

// Round 3
// 60.942 us; speedup vs baseline: 1.1606x; 1.1606x over previous
//
#include <hip/hip_runtime.h>

// CrossNet, two-phase. Closed form: x_k = x*c_k + cumsum(b)_k with per-row
// scalars c_k from 3 dots (x.w_i) + 2 shared constants (b-derived).
// Kernel A: per-row scalars (HBM read-only stream of x).
// Kernel B: streaming emit; x re-read is L3-resident, HBM ~write-only.
// NOTE R2 lesson: __builtin_nontemporal_* on gfx950 regressed 45.9->70.7us.

constexpr int BLK = 256;

typedef float f32x4 __attribute__((ext_vector_type(4)));

__device__ __forceinline__ float dot4(f32x4 a, f32x4 b) {
    return a.x * b.x + a.y * b.y + a.z * b.z + a.w * b.w;
}

// ---------------- Kernel A: per-row scalars c1,c2,c3 -> ws[row] ------------
__global__ __launch_bounds__(BLK) void crossnet_scalars(
    const float* __restrict__ x,
    const float* __restrict__ w,
    const float* __restrict__ b,
    float* __restrict__ cs,   // [B] of f32x4 (c1,c2,c3,pad)
    int N)
{
    const int row = blockIdx.x;
    const int tid = threadIdx.x;

    const f32x4* x4 = (const f32x4*)(x + (size_t)row * N);
    const f32x4* w0 = (const f32x4*)(w);
    const f32x4* w1 = (const f32x4*)(w + N);
    const f32x4* w2 = (const f32x4*)(w + 2 * (size_t)N);
    const f32x4* b0 = (const f32x4*)(b);
    const f32x4* b1 = (const f32x4*)(b + N);

    float p0 = 0.f, p1 = 0.f, p2 = 0.f;  // x . w0/w1/w2
    float q1 = 0.f, q2 = 0.f;            // b0 . w1, (b0+b1) . w2

    #pragma unroll
    for (int c = 0; c < 4; ++c) {
        const int idx = c * BLK + tid;
        const f32x4 xx = x4[idx];
        const f32x4 wa = w0[idx];
        const f32x4 wb = w1[idx];
        const f32x4 wc = w2[idx];
        const f32x4 ba = b0[idx];
        const f32x4 bb = b1[idx];
        p0 += dot4(xx, wa);
        p1 += dot4(xx, wb);
        p2 += dot4(xx, wc);
        q1 += dot4(ba, wb);
        q2 += dot4(ba + bb, wc);
    }

    #pragma unroll
    for (int off = 32; off > 0; off >>= 1) {
        p0 += __shfl_down(p0, off);
        p1 += __shfl_down(p1, off);
        p2 += __shfl_down(p2, off);
        q1 += __shfl_down(q1, off);
        q2 += __shfl_down(q2, off);
    }

    __shared__ float red[4][8];
    const int wave = tid >> 6;
    const int lane = tid & 63;
    if (lane == 0) {
        red[wave][0] = p0; red[wave][1] = p1; red[wave][2] = p2;
        red[wave][3] = q1; red[wave][4] = q2;
    }
    __syncthreads();

    if (tid == 0) {
        const float u0 = red[0][0] + red[1][0] + red[2][0] + red[3][0];
        const float u1 = red[0][1] + red[1][1] + red[2][1] + red[3][1];
        const float u2 = red[0][2] + red[1][2] + red[2][2] + red[3][2];
        const float t1 = red[0][3] + red[1][3] + red[2][3] + red[3][3];
        const float t2 = red[0][4] + red[1][4] + red[2][4] + red[3][4];

        const float c1 = 1.0f + u0;
        const float s1 = c1 * u1 + t1;
        const float c2 = c1 + s1;
        const float s2 = c2 * u2 + t2;
        const float c3 = c2 + s2;

        f32x4 o; o.x = c1; o.y = c2; o.z = c3; o.w = 0.f;
        ((f32x4*)cs)[row] = o;
    }
}

// ---------------- Kernel B: streaming emit ---------------------------------
__global__ __launch_bounds__(BLK) void crossnet_emit(
    const float* __restrict__ x,
    const float* __restrict__ b,
    const float* __restrict__ cs,
    float* __restrict__ out,
    int B, int N)
{
    const int row = blockIdx.x;
    const int tid = threadIdx.x;
    const size_t base = (size_t)row * N;

    const f32x4 c = ((const f32x4*)cs)[row];  // uniform per block

    const f32x4* x4 = (const f32x4*)(x + base);
    const f32x4* b0 = (const f32x4*)(b);
    const f32x4* b1 = (const f32x4*)(b + N);
    const f32x4* b2 = (const f32x4*)(b + 2 * (size_t)N);

    f32x4* o0 = (f32x4*)(out + base);
    f32x4* o1 = (f32x4*)(out + (size_t)B * N + base);
    f32x4* o2 = (f32x4*)(out + 2 * (size_t)B * N + base);

    #pragma unroll
    for (int cc = 0; cc < 4; ++cc) {
        const int idx = cc * BLK + tid;
        const f32x4 xx = x4[idx];   // L3-resident (read by kernel A)
        const f32x4 ba = b0[idx];   // L2-resident (48 KB total)
        const f32x4 bb = b1[idx];
        const f32x4 bc = b2[idx];
        const f32x4 cb2 = ba + bb;
        const f32x4 cb3 = cb2 + bc;
        o0[idx] = xx * c.x + ba;
        o1[idx] = xx * c.y + cb2;
        o2[idx] = xx * c.z + cb3;
    }
}

extern "C" void kernel_launch(void* const* d_in, const int* in_sizes, int n_in,
                              void* d_out, int out_size, void* d_ws, size_t ws_size,
                              hipStream_t stream) {
    const float* x = (const float*)d_in[0];
    const float* w = (const float*)d_in[1];
    const float* b = (const float*)d_in[2];
    float* out = (float*)d_out;
    float* cs = (float*)d_ws;  // B * 4 floats = 64 KB

    const int N = in_sizes[1] / 3;   // w is [3, N, 1]
    const int B = in_sizes[0] / N;   // x is [B, N]

    crossnet_scalars<<<B, BLK, 0, stream>>>(x, w, b, cs, N);
    crossnet_emit<<<B, BLK, 0, stream>>>(x, b, cs, out, B, N);
}

// Round 4
// 53.918 us; speedup vs baseline: 1.3119x; 1.1303x over previous
//
#include <hip/hip_runtime.h>

// CrossNet fused, wave-per-row, ZERO barriers. Closed form:
//   x_k = x*c_k + cumsum(b)_k ; c_k per-row scalars from 3 dots + 2 consts.
// One 64-lane wave owns one row: x cached in regs (16 f32x4/lane),
// wave-local __shfl_xor butterfly reduce (no LDS, no __syncthreads),
// then streaming emit. b re-read in emit (48 KB, L2-resident).
// History: R1 fused block-per-row 45.9us; R2 nontemporal 70.7us (BAD);
// R3 two-phase split 60.9us (BAD). This removes R1's block barrier.

constexpr int BLK = 256;           // 4 independent waves per block
constexpr int ROWS_PER_BLK = 4;

typedef float f32x4 __attribute__((ext_vector_type(4)));

__device__ __forceinline__ float dot4(f32x4 a, f32x4 b) {
    return a.x * b.x + a.y * b.y + a.z * b.z + a.w * b.w;
}

__global__ __launch_bounds__(BLK) void crossnet_wave(
    const float* __restrict__ x,
    const float* __restrict__ w,
    const float* __restrict__ b,
    float* __restrict__ out,
    int B, int N)
{
    const int wave = threadIdx.x >> 6;
    const int lane = threadIdx.x & 63;
    const int row  = blockIdx.x * ROWS_PER_BLK + wave;

    const size_t base = (size_t)row * N;
    const f32x4* x4 = (const f32x4*)(x + base);
    const f32x4* w0 = (const f32x4*)(w);
    const f32x4* w1 = (const f32x4*)(w + N);
    const f32x4* w2 = (const f32x4*)(w + 2 * (size_t)N);
    const f32x4* b0 = (const f32x4*)(b);
    const f32x4* b1 = (const f32x4*)(b + N);
    const f32x4* b2 = (const f32x4*)(b + 2 * (size_t)N);

    // x row cached in registers: 16 f32x4 per lane (64 VGPR)
    f32x4 xv[16];

    float p0 = 0.f, p1 = 0.f, p2 = 0.f;  // x . w0/w1/w2
    float q1 = 0.f, q2 = 0.f;            // b0 . w1, (b0+b1) . w2

    #pragma unroll
    for (int i = 0; i < 16; ++i) {
        const int idx = i * 64 + lane;       // 1 KB contiguous per wave-iter
        const f32x4 xx = x4[idx];
        const f32x4 wa = w0[idx];
        const f32x4 wb = w1[idx];
        const f32x4 wc = w2[idx];
        const f32x4 ba = b0[idx];
        const f32x4 bb = b1[idx];
        xv[i] = xx;
        p0 += dot4(xx, wa);
        p1 += dot4(xx, wb);
        p2 += dot4(xx, wc);
        q1 += dot4(ba, wb);
        q2 += dot4(ba + bb, wc);
    }

    // 64-lane butterfly: every lane ends with the full row sum. No LDS.
    #pragma unroll
    for (int off = 1; off < 64; off <<= 1) {
        p0 += __shfl_xor(p0, off);
        p1 += __shfl_xor(p1, off);
        p2 += __shfl_xor(p2, off);
        q1 += __shfl_xor(q1, off);
        q2 += __shfl_xor(q2, off);
    }

    // scalar recurrence (uniform across the wave)
    const float c1 = 1.0f + p0;          // x1 = x*c1 + b0
    const float s1 = c1 * p1 + q1;
    const float c2 = c1 + s1;            // x2 = x*c2 + b0+b1
    const float s2 = c2 * p2 + q2;
    const float c3 = c2 + s2;            // x3 = x*c3 + b0+b1+b2

    f32x4* o0 = (f32x4*)(out + base);
    f32x4* o1 = (f32x4*)(out + (size_t)B * N + base);
    f32x4* o2 = (f32x4*)(out + 2 * (size_t)B * N + base);

    #pragma unroll
    for (int i = 0; i < 16; ++i) {
        const int idx = i * 64 + lane;
        const f32x4 ba = b0[idx];        // L2-hit (48 KB shared by all)
        const f32x4 bb = b1[idx];
        const f32x4 bc = b2[idx];
        const f32x4 cb2 = ba + bb;
        const f32x4 cb3 = cb2 + bc;
        o0[idx] = xv[i] * c1 + ba;
        o1[idx] = xv[i] * c2 + cb2;
        o2[idx] = xv[i] * c3 + cb3;
    }
}

extern "C" void kernel_launch(void* const* d_in, const int* in_sizes, int n_in,
                              void* d_out, int out_size, void* d_ws, size_t ws_size,
                              hipStream_t stream) {
    const float* x = (const float*)d_in[0];
    const float* w = (const float*)d_in[1];
    const float* b = (const float*)d_in[2];
    float* out = (float*)d_out;

    const int N = in_sizes[1] / 3;   // w is [3, N, 1]
    const int B = in_sizes[0] / N;   // x is [B, N]

    crossnet_wave<<<B / ROWS_PER_BLK, BLK, 0, stream>>>(x, w, b, out, B, N);
}